// Round 3
// baseline (973.799 us; speedup 1.0000x reference)
//
#include <hip/hip_runtime.h>
#include <hip/hip_bf16.h>

// SDE Euler-Maruyama: x_{k+1} = x_k + dt*(x_k @ A^T) + (sigma*sqrt(dt))*dW_k
// out[0] = x0, out[k+1] = x_{k+1}, out shape [1001, 1024, 256].
//
// R1: 880us latency-bound. R2: lgkm-only barrier, -3.5% (vmcnt drain was not
// the stall; two-phase structure was).
// R3: update in MFMA C/D layout (lanes 0-15 hold x as 16 f32 regs) ->
//   - no drift LDS round-trip, no second barrier
//   - double-buffered xb (bf16 x) -> ONE barrier/step
//   - dW/out accessed in C/D layout (16x64B transactions, lines fully used)
//   - out store of step n deferred into step n+1's MFMA window

typedef __attribute__((ext_vector_type(4))) float fvec4;
typedef __attribute__((ext_vector_type(8))) short svec8;
typedef __attribute__((ext_vector_type(4))) float f32x4;

constexpr int D = 256;
constexpr int BATCH = 1024;
constexpr int BD = BATCH * D;
constexpr int NSTEPS = 1000;
constexpr float DT = 0.001f;
constexpr float SQRT_DT = 0.03162277660168379f;  // sqrt(0.001)

__device__ __forceinline__ unsigned short f2bf(float f) {
  // round-to-nearest-even f32 -> bf16
  unsigned int u = __float_as_uint(f);
  u += 0x7FFFu + ((u >> 16) & 1u);
  return (unsigned short)(u >> 16);
}

// LDS-only barrier: no vmcnt drain (global loads/stores stay in flight).
__device__ __forceinline__ void lds_barrier() {
  __builtin_amdgcn_sched_barrier(0);
  asm volatile("s_waitcnt lgkmcnt(0)" ::: "memory");
  __builtin_amdgcn_s_barrier();
  __builtin_amdgcn_sched_barrier(0);
}

// xb swizzle: element index = (row<<8) ^ col ^ (row<<5), bits disjoint where
// needed (col = w*64 | tt*16 | l, l<16). Reader fragment base:
// fb = (rr<<8)|(q<<3)|(rr<<5); per-kt address = fb ^ (kt<<5).

__global__ __launch_bounds__(256, 1)
void sde_em_kernel(const float* __restrict__ x0, const float* __restrict__ Amat,
                   const float* __restrict__ sigma, const float* __restrict__ dW,
                   float* __restrict__ out) {
  __shared__ __align__(16) unsigned short xb[2][4 * 256];  // double-buffered bf16 x

  const int t = threadIdx.x;
  const int w = t >> 6;
  const int l = t & 63;
  const int l16 = l & 15;

  // ---- one-time: A fragments (GEMM B-operand) into registers, bf16 ----
  // B-frag layout (16x16x32): lane holds col n = l&15, k = (l>>4)*8 + i
  svec8 bfr[4][8];
  {
    const int nbase = (w << 6) + l16;        // + tt*16
    const int kb = (l >> 4) << 3;            // + kt*32
#pragma unroll
    for (int tt = 0; tt < 4; ++tt) {
#pragma unroll
      for (int kt = 0; kt < 8; ++kt) {
        const float* src = Amat + (size_t)(nbase + (tt << 4)) * D + (kt << 5) + kb;
        fvec4 a0 = *(const fvec4*)(src);
        fvec4 a1 = *(const fvec4*)(src + 4);
        svec8 b;
        b[0] = (short)f2bf(a0[0]); b[1] = (short)f2bf(a0[1]);
        b[2] = (short)f2bf(a0[2]); b[3] = (short)f2bf(a0[3]);
        b[4] = (short)f2bf(a1[0]); b[5] = (short)f2bf(a1[1]);
        b[6] = (short)f2bf(a1[2]); b[7] = (short)f2bf(a1[3]);
        bfr[tt][kt] = b;
      }
    }
  }

  // ---- C/D-layout state: lane l (<16) holds x[path r][dim w*64+tt*16+l] ----
  // global base offset for (tt, r) = gbase + r*D + tt*16
  const size_t gbase = (size_t)(blockIdx.x << 2) * D + (w << 6) + l16;

  float sg[4];
#pragma unroll
  for (int tt = 0; tt < 4; ++tt)
    sg[tt] = sigma[(w << 6) + (tt << 4) + l16] * SQRT_DT;

  float xs[4][4];
#pragma unroll
  for (int tt = 0; tt < 4; ++tt)
#pragma unroll
    for (int r = 0; r < 4; ++r)
      xs[tt][r] = x0[gbase + r * D + (tt << 4)];

  // seed xb[0] with bf16(x0)
  const int wbase = (w << 6) + l16;  // bits 0-3, 6-7
  if (l < 16) {
#pragma unroll
    for (int tt = 0; tt < 4; ++tt)
#pragma unroll
      for (int r = 0; r < 4; ++r)
        xb[0][wbase ^ ((r << 8) ^ (tt << 4) ^ (r << 5))] = f2bf(xs[tt][r]);
  }

  // fragment-read base (A operand): row rr = (l&15)&3 (rows 4-15 duplicate
  // paths 0-3; their outputs land in lanes >=16 and are never used)
  const int rr = l16 & 3;
  const int q = l >> 4;
  const int fb = (rr << 8) | (q << 3) | (rr << 5);  // disjoint bits

  // prefetch dW[0]
  float dwA[4][4], dwB[4][4];
#pragma unroll
  for (int tt = 0; tt < 4; ++tt)
#pragma unroll
    for (int r = 0; r < 4; ++r)
      dwA[tt][r] = __builtin_nontemporal_load(dW + gbase + r * D + (tt << 4));

  __syncthreads();

#define STEP(n_, CUR, NXT, RB, WB)                                             \
  {                                                                            \
    const int np1_ = ((n_) + 1 < NSTEPS) ? ((n_) + 1) : (NSTEPS - 1);          \
    const float* dwp_ = dW + (size_t)np1_ * BD + gbase;                        \
    _Pragma("unroll") for (int tt = 0; tt < 4; ++tt)                           \
        _Pragma("unroll") for (int r = 0; r < 4; ++r)                          \
            NXT[tt][r] =                                                       \
                __builtin_nontemporal_load(dwp_ + r * D + (tt << 4));          \
    /* store out[n] = current xs (overlaps this step's MFMA) */                \
    if (l < 16) {                                                              \
      float* op_ = out + (size_t)(n_) * BD + gbase;                            \
      _Pragma("unroll") for (int tt = 0; tt < 4; ++tt)                         \
          _Pragma("unroll") for (int r = 0; r < 4; ++r)                        \
              __builtin_nontemporal_store(xs[tt][r],                           \
                                          op_ + r * D + (tt << 4));            \
    }                                                                          \
    f32x4 acc[4];                                                              \
    _Pragma("unroll") for (int tt = 0; tt < 4; ++tt) acc[tt] =                 \
        (f32x4){0.f, 0.f, 0.f, 0.f};                                           \
    _Pragma("unroll") for (int kt = 0; kt < 8; ++kt) {                         \
      svec8 a = *(const svec8*)&xb[RB][fb ^ (kt << 5)];                        \
      _Pragma("unroll") for (int tt = 0; tt < 4; ++tt) acc[tt] =               \
          __builtin_amdgcn_mfma_f32_16x16x32_bf16(a, bfr[tt][kt], acc[tt], 0,  \
                                                  0, 0);                       \
    }                                                                          \
    if (l < 16) {                                                              \
      _Pragma("unroll") for (int tt = 0; tt < 4; ++tt)                         \
          _Pragma("unroll") for (int r = 0; r < 4; ++r) {                      \
        xs[tt][r] = __builtin_fmaf(                                            \
            DT, acc[tt][r],                                                    \
            __builtin_fmaf(sg[tt], CUR[tt][r], xs[tt][r]));                    \
        xb[WB][wbase ^ ((r << 8) ^ (tt << 4) ^ (r << 5))] = f2bf(xs[tt][r]);   \
      }                                                                        \
    }                                                                          \
    lds_barrier();                                                             \
  }

  for (int n = 0; n < NSTEPS; n += 2) {
    STEP(n, dwA, dwB, 0, 1);
    STEP(n + 1, dwB, dwA, 1, 0);
  }
#undef STEP

  // final state -> out[NSTEPS]
  if (l < 16) {
    float* op = out + (size_t)NSTEPS * BD + gbase;
#pragma unroll
    for (int tt = 0; tt < 4; ++tt)
#pragma unroll
      for (int r = 0; r < 4; ++r)
        __builtin_nontemporal_store(xs[tt][r], op + r * D + (tt << 4));
  }
}

extern "C" void kernel_launch(void* const* d_in, const int* in_sizes, int n_in,
                              void* d_out, int out_size, void* d_ws, size_t ws_size,
                              hipStream_t stream) {
  const float* x0    = (const float*)d_in[0];
  const float* Amat  = (const float*)d_in[1];
  const float* sigma = (const float*)d_in[2];
  const float* dW    = (const float*)d_in[3];
  float* out = (float*)d_out;
  sde_em_kernel<<<dim3(256), dim3(256), 0, stream>>>(x0, Amat, sigma, dW, out);
}

// Round 4
// 632.644 us; speedup vs baseline: 1.5393x; 1.5393x over previous
//
#include <hip/hip_runtime.h>
#include <hip/hip_bf16.h>

// SDE Euler-Maruyama: x_{k+1} = x_k + dt*(x_k @ A^T) + (sigma*sqrt(dt))*dW_k
// out[0] = x0, out[k+1] = x_{k+1}, out shape [1001, 1024, 256].
//
// R1 880us: latency-bound, 1 wave/SIMD. R2 849us: lgkm-only barriers (-3.5%).
// R3 973us: C/D-layout update REGRESSED (scalar 4B global ops, no TLP cover).
// R4: TLP. 512-thread blocks = 8 waves = 2 waves/SIMD; one wave's VALU/LDS/
// barrier time hides under the other's MFMA. Wave owns 32 MFMA cols (2 acc
// chains); update thread owns (path, 2 dims) -> fvec2 global I/O. xb double-
// buffered; dr exchange kept (vectorized I/O beats barrier removal, per R3).

typedef __attribute__((ext_vector_type(2))) float fvec2;
typedef __attribute__((ext_vector_type(4))) float fvec4;
typedef __attribute__((ext_vector_type(8))) short svec8;
typedef __attribute__((ext_vector_type(4))) float f32x4;

constexpr int D = 256;
constexpr int BATCH = 1024;
constexpr int BD = BATCH * D;
constexpr int NSTEPS = 1000;
constexpr float DT = 0.001f;
constexpr float SQRT_DT = 0.03162277660168379f;  // sqrt(0.001)

__device__ __forceinline__ unsigned short f2bf(float f) {
  // round-to-nearest-even f32 -> bf16
  unsigned int u = __float_as_uint(f);
  u += 0x7FFFu + ((u >> 16) & 1u);
  return (unsigned short)(u >> 16);
}

// LDS-only barrier: no vmcnt drain (global loads/stores stay in flight).
__device__ __forceinline__ void lds_barrier() {
  __builtin_amdgcn_sched_barrier(0);
  asm volatile("s_waitcnt lgkmcnt(0)" ::: "memory");
  __builtin_amdgcn_s_barrier();
  __builtin_amdgcn_sched_barrier(0);
}

__global__ __launch_bounds__(512, 2)
void sde_em_kernel(const float* __restrict__ x0, const float* __restrict__ Amat,
                   const float* __restrict__ sigma, const float* __restrict__ dW,
                   float* __restrict__ out) {
  // xb: double-buffered bf16 x, 4 paths x 256 dims, XOR-swizzled (^ row<<5)
  __shared__ __align__(16) unsigned short xb[2][4 * 256];
  // dr: fp32 drift tile, 4 paths x 256 dims
  __shared__ __align__(16) float dr[4 * 256];

  const int t = threadIdx.x;
  const int w = t >> 6;          // wave 0..7
  const int l = t & 63;
  const int l16 = l & 15;

  // ---- MFMA role: wave w owns output cols w*32 .. w*32+31 ----
  // B-frag (16x16x32): lane holds col n = l&15, k = (l>>4)*8 + i
  svec8 bfr[2][8];
  {
    const int nbase = (w << 5) + l16;        // + tt*16
    const int kb = (l >> 4) << 3;            // + kt*32
#pragma unroll
    for (int tt = 0; tt < 2; ++tt) {
#pragma unroll
      for (int kt = 0; kt < 8; ++kt) {
        const float* src = Amat + (size_t)(nbase + (tt << 4)) * D + (kt << 5) + kb;
        fvec4 a0 = *(const fvec4*)(src);
        fvec4 a1 = *(const fvec4*)(src + 4);
        svec8 b;
        b[0] = (short)f2bf(a0[0]); b[1] = (short)f2bf(a0[1]);
        b[2] = (short)f2bf(a0[2]); b[3] = (short)f2bf(a0[3]);
        b[4] = (short)f2bf(a1[0]); b[5] = (short)f2bf(a1[1]);
        b[6] = (short)f2bf(a1[2]); b[7] = (short)f2bf(a1[3]);
        bfr[tt][kt] = b;
      }
    }
  }

  // ---- update role: thread owns (path pt, dims cb..cb+1) ----
  const int pt = w >> 1;                     // path 0..3
  const int cb = ((w & 1) << 7) + (l << 1);  // dim 0..254 (even)
  const size_t goff = (size_t)((blockIdx.x << 2) + pt) * D + cb;
  const int xwi = (pt << 8) + (cb ^ (pt << 5));  // xb write index (u32-aligned)

  fvec2 sg = *(const fvec2*)(sigma + cb);
  sg *= SQRT_DT;
  fvec2 xs = *(const fvec2*)(x0 + goff);

  // out[0] = x0
  __builtin_nontemporal_store(xs, (fvec2*)(out + goff));

  // seed xb[0]
  *(unsigned int*)&xb[0][xwi] =
      (unsigned int)f2bf(xs[0]) | ((unsigned int)f2bf(xs[1]) << 16);

  // A-frag read addressing: row rr = (l&15)&3 (rows 4-15 duplicate paths 0-3;
  // their C/D rows land in lanes >= 16, never stored)
  const int rr = l16 & 3;
  const int q = l >> 4;

  // 2-deep dW prefetch
  fvec2 dwA = __builtin_nontemporal_load((const fvec2*)(dW + goff));
  fvec2 dwB = __builtin_nontemporal_load((const fvec2*)(dW + BD + goff));

  __syncthreads();

#define STEP(n_, CUR, RB, WB)                                                  \
  {                                                                            \
    const int nn_ = ((n_) + 2 < NSTEPS) ? ((n_) + 2) : (NSTEPS - 1);           \
    fvec2 nw_ = __builtin_nontemporal_load(                                    \
        (const fvec2*)(dW + (size_t)nn_ * BD + goff));                         \
    f32x4 acc[2];                                                              \
    acc[0] = (f32x4){0.f, 0.f, 0.f, 0.f};                                      \
    acc[1] = (f32x4){0.f, 0.f, 0.f, 0.f};                                      \
    _Pragma("unroll") for (int kt = 0; kt < 8; ++kt) {                         \
      svec8 a = *(const svec8*)                                                \
          &xb[RB][(rr << 8) + (((kt << 5) + (q << 3)) ^ (rr << 5))];           \
      acc[0] = __builtin_amdgcn_mfma_f32_16x16x32_bf16(a, bfr[0][kt], acc[0],  \
                                                       0, 0, 0);               \
      acc[1] = __builtin_amdgcn_mfma_f32_16x16x32_bf16(a, bfr[1][kt], acc[1],  \
                                                       0, 0, 0);               \
    }                                                                          \
    /* C/D: col = lane&15 (output dim), row = path = reg (lanes 0-15) */       \
    if (l < 16) {                                                              \
      _Pragma("unroll") for (int tt = 0; tt < 2; ++tt)                         \
          _Pragma("unroll") for (int r = 0; r < 4; ++r)                        \
              dr[(r << 8) + (w << 5) + (tt << 4) + l16] = acc[tt][r];          \
    }                                                                          \
    lds_barrier();                                                             \
    fvec2 df = *(const fvec2*)&dr[(pt << 8) + cb];                             \
    xs[0] = __builtin_fmaf(DT, df[0], __builtin_fmaf(sg[0], CUR[0], xs[0]));   \
    xs[1] = __builtin_fmaf(DT, df[1], __builtin_fmaf(sg[1], CUR[1], xs[1]));   \
    __builtin_nontemporal_store(                                               \
        xs, (fvec2*)(out + (size_t)((n_) + 1) * BD + goff));                   \
    *(unsigned int*)&xb[WB][xwi] =                                             \
        (unsigned int)f2bf(xs[0]) | ((unsigned int)f2bf(xs[1]) << 16);         \
    CUR = nw_;                                                                 \
    lds_barrier();                                                             \
  }

  for (int n = 0; n < NSTEPS; n += 2) {
    STEP(n, dwA, 0, 1);
    STEP(n + 1, dwB, 1, 0);
  }
#undef STEP
}

extern "C" void kernel_launch(void* const* d_in, const int* in_sizes, int n_in,
                              void* d_out, int out_size, void* d_ws, size_t ws_size,
                              hipStream_t stream) {
  const float* x0    = (const float*)d_in[0];
  const float* Amat  = (const float*)d_in[1];
  const float* sigma = (const float*)d_in[2];
  const float* dW    = (const float*)d_in[3];
  float* out = (float*)d_out;
  sde_em_kernel<<<dim3(256), dim3(512), 0, stream>>>(x0, Amat, sigma, dW, out);
}